// Round 1
// baseline (56.152 us; speedup 1.0000x reference)
//
#include <hip/hip_runtime.h>
#include <math.h>

// Grayscale morphological dilation, 7x7 additive SE, zero 'same' padding:
//   out[p, i, j] = max_{a,b in 0..6} ( xz(p, i+a-3, j+b-3) + w[a,b] )
// where xz is x zero-extended outside [0,512)x[0,512).
//
// Thread tile: 4 wide x 7 tall, streaming-accumulator over the 13 input rows
// that touch the tile. All arrays static-indexed (full unroll) -> registers.
// Loads are 16B-aligned float4 (col base multiple of 4, W=512), so every
// chunk is fully in-bounds or fully out-of-bounds -> exact zero-fill.

#define HH 512
#define WW 512

__device__ __forceinline__ float4 ld4(const float* p, bool ok) {
  float4 v = make_float4(0.f, 0.f, 0.f, 0.f);
  if (ok) v = *reinterpret_cast<const float4*>(p);
  return v;
}

__global__ __launch_bounds__(256) void dilate7(const float* __restrict__ x,
                                               const float* __restrict__ wg,
                                               float* __restrict__ out) {
  const int tid = threadIdx.x;
  const int lc = tid & 63;          // 64 thread-cols per block
  const int tr = tid >> 6;          // 4 thread-rows per block
  const int col0 = blockIdx.x * 256 + lc * 4;   // output col base (mult of 4)
  const int row0 = blockIdx.y * 28 + tr * 7;    // output row base

  const size_t plane_off = (size_t)blockIdx.z * (size_t)(HH * WW);
  const float* xp = x + plane_off;
  float* op = out + plane_off;

  // Uniform-address loads -> scalar (SGPR) weights.
  float wv[49];
#pragma unroll
  for (int i = 0; i < 49; ++i) wv[i] = wg[i];

  float acc[7][4];
#pragma unroll
  for (int t = 0; t < 7; ++t)
#pragma unroll
    for (int j = 0; j < 4; ++j) acc[t][j] = -INFINITY;

  const bool okL = (col0 >= 4);         // left halo chunk in-bounds?
  const bool okR = (col0 + 8 <= WW);    // right halo chunk in-bounds?

#pragma unroll
  for (int k = 0; k < 13; ++k) {
    const int r = row0 - 3 + k;                 // input row for this step
    const bool rok = (r >= 0) && (r < HH);
    const float* rp = xp + (size_t)r * WW + col0;
    float4 v0 = ld4(rp - 4, rok && okL);        // cols col0-4 .. col0-1
    float4 v1 = ld4(rp, rok);                   // cols col0   .. col0+3
    float4 v2 = ld4(rp + 4, rok && okR);        // cols col0+4 .. col0+7
    const float rv[12] = {v0.x, v0.y, v0.z, v0.w,
                          v1.x, v1.y, v1.z, v1.w,
                          v2.x, v2.y, v2.z, v2.w};

    const int tlo = (k > 6) ? (k - 6) : 0;
    const int thi = (k < 6) ? k : 6;
#pragma unroll
    for (int t = 0; t < 7; ++t) {
      if (t < tlo || t > thi) continue;         // folds away (k is constant)
      const int a = k - t;                      // SE row feeding out-row t
#pragma unroll
      for (int j = 0; j < 4; ++j) {
        // input col for tap b: col0 + j + b - 3 -> rv[j + 1 + b]
        float m = acc[t][j];
        float c0 = rv[j + 1] + wv[a * 7 + 0];
        float c1 = rv[j + 2] + wv[a * 7 + 1];
        m = fmaxf(m, fmaxf(c0, c1));            // -> v_max3_f32
        float c2 = rv[j + 3] + wv[a * 7 + 2];
        float c3 = rv[j + 4] + wv[a * 7 + 3];
        m = fmaxf(m, fmaxf(c2, c3));
        float c4 = rv[j + 5] + wv[a * 7 + 4];
        float c5 = rv[j + 6] + wv[a * 7 + 5];
        m = fmaxf(m, fmaxf(c4, c5));
        float c6 = rv[j + 7] + wv[a * 7 + 6];
        m = fmaxf(m, c6);
        acc[t][j] = m;
      }
    }
  }

#pragma unroll
  for (int t = 0; t < 7; ++t) {
    const int rr = row0 + t;
    if (rr < HH) {
      float4 o = make_float4(acc[t][0], acc[t][1], acc[t][2], acc[t][3]);
      *reinterpret_cast<float4*>(op + (size_t)rr * WW + col0) = o;
    }
  }
}

extern "C" void kernel_launch(void* const* d_in, const int* in_sizes, int n_in,
                              void* d_out, int out_size, void* d_ws, size_t ws_size,
                              hipStream_t stream) {
  const float* x = (const float*)d_in[0];
  const float* w = (const float*)d_in[1];
  float* out = (float*)d_out;
  const int planes = in_sizes[0] / (HH * WW);   // 8*8 = 64
  // cols: 2 blocks * 256; rows: ceil(512/28) = 19 blocks * 28
  dim3 grid(2, 19, planes);
  dilate7<<<grid, dim3(256, 1, 1), 0, stream>>>(x, w, out);
}